// Round 6
// baseline (244.529 us; speedup 1.0000x reference)
//
#include <hip/hip_runtime.h>
#include <stdint.h>
#include <math.h>

#define NN 50000
#define DD 64
#define EE 800000
#define BSZ 64                      // nodes per bucket
#define NB 782                      // ceil(NN / BSZ)
#define BCAP 1280                   // records per bucket; mean 1023, sd ~32 -> +8 sigma
#define EPW 4096                    // edges per bucketize workgroup -> 196 WGs
#define CAP 48                      // dense slots per node; P(deg>48) ~ 1e-6 total
#define BIGMAX 1024                 // capacity of the dg>32 node list (expected ~2)

// workspace layout (unchanged footprint, ends at 26.31 MiB):
//   [0, 3132B)         bucket_cnt[NB] + big_cnt (at index NB)
//   [4KB, 8KB)         big_list[BIGMAX]
//   [16KB, 216KB)      deg[NN]          (clamped to CAP)
//   [256KB, 8.27MB)    recs[NB][BCAP]   packed (w_bits<<32 | src<<6 | dst_local)
//   [8MiB, 26.31MiB)   slots[NN][CAP]   dense (w_bits<<32 | src)

// ---------------- kernel 0: zero bucket counters (+big_cnt) ----------------
__global__ void zero_cnt(int* __restrict__ cnt) {
    int i = blockIdx.x * blockDim.x + threadIdx.x;
    if (i < NB + 1) cnt[i] = 0;
}

// ---------------- kernel 1: counting-sort edges into dst-buckets ----------------
// LDS-staged single global read of the edge slice; per-WG LDS histogram; ONE
// global atomic per (WG,bucket) chunk; records stored into contiguous chunks.
__global__ __launch_bounds__(512) void bucketize(
        const int* __restrict__ ei, const float* __restrict__ ew,
        int* __restrict__ bucket_cnt, uint64_t* __restrict__ recs) {
    __shared__ int   hist[NB];
    __shared__ int   base[NB];
    __shared__ int   eL[EPW];
    __shared__ int   dL[EPW];
    __shared__ float wL[EPW];   // 48KB staging + 6.3KB hist/base
    const int t = threadIdx.x;
    const int e0 = blockIdx.x * EPW;
    const int nE = (e0 + EPW < EE) ? EPW : (EE - e0);

    for (int i = t; i < NB; i += 512) hist[i] = 0;
    for (int i = t; i < nE; i += 512) {         // stage edges once (coalesced)
        eL[i] = ei[e0 + i];
        dL[i] = ei[EE + e0 + i];
        wL[i] = ew[e0 + i];
    }
    __syncthreads();

    for (int i = t; i < nE; i += 512)           // pass 1: histogram (LDS atomics)
        atomicAdd(&hist[dL[i] >> 6], 1);
    __syncthreads();

    for (int i = t; i < NB; i += 512) {         // one global atomic per chunk
        int c = hist[i];
        base[i] = (c > 0) ? atomicAdd(&bucket_cnt[i], c) : 0;
        hist[i] = 0;                            // reuse as running offset
    }
    __syncthreads();

    for (int i = t; i < nE; i += 512) {         // pass 2: place records (from LDS)
        int d = dL[i];
        int b = d >> 6;
        int p = base[b] + atomicAdd(&hist[b], 1);
        if (p < BCAP)
            recs[(size_t)b * BCAP + p] =
                ((uint64_t)__float_as_uint(wL[i]) << 32) |
                ((uint32_t)eL[i] << 6) | (uint32_t)(d & 63);
    }
}

// ---------------- kernel 2: bin records into dense per-node slot rows ----------
// One WG per bucket. LDS atomics give dense positions; slot matrix streams out
// coalesced. Also emits the (rare) dg>32 node list for the big-median kernel.
__global__ __launch_bounds__(256) void bin_dense(
        const int* __restrict__ bucket_cnt, const uint64_t* __restrict__ recs,
        uint64_t* __restrict__ slots, int* __restrict__ deg,
        int* __restrict__ big_cnt, int* __restrict__ big_list) {
    __shared__ uint64_t sl[BSZ * CAP];          // 24.5 KB
    __shared__ int degl[BSZ];
    const int t = threadIdx.x;
    const int b = blockIdx.x;

    int cnt = bucket_cnt[b];
    if (cnt > BCAP) cnt = BCAP;

    for (int i = t; i < BSZ; i += 256) degl[i] = 0;
    __syncthreads();

    const uint64_t* br = recs + (size_t)b * BCAP;
    for (int i = t; i < cnt; i += 256) {
        uint64_t r = br[i];                     // coalesced
        int loc = (int)(r & 63u);
        int p = atomicAdd(&degl[loc], 1);       // LDS atomic -> dense positions
        if (p < CAP)
            sl[loc * CAP + p] = (r & 0xFFFFFFFF00000000ull)    // w_bits
                              | (uint32_t)(((uint32_t)r) >> 6); // src
    }
    __syncthreads();

    uint64_t* outrow = slots + (size_t)b * BSZ * CAP;
    for (int i = t; i < BSZ * CAP; i += 256) outrow[i] = sl[i];   // stream out
    int n0 = b * BSZ;
    for (int i = t; i < BSZ; i += 256) {
        int n = n0 + i;
        if (n < NN) {
            int dgi = degl[i];
            if (dgi > CAP) dgi = CAP;
            deg[n] = dgi;
            if (dgi > 32) {                     // expected ~2 nodes total
                int q = atomicAdd(big_cnt, 1);
                if (q < BIGMAX) big_list[q] = n;
            }
        }
    }
}

// ---------------- Batcher odd-even mergesort, all-constexpr indices ----------
// AW = physical array size (may exceed network size N for prefix sorts).
__device__ __forceinline__ void cswap(float& a, float& b) {
    float lo = fminf(a, b);
    float hi = fmaxf(a, b);
    a = lo; b = hi;
}

template<int I, int END, int R, int STEP, int AW>
struct Pairs {
    static __device__ __forceinline__ void run(float (&r)[AW]) {
        if constexpr (I + R < END) {
            cswap(r[I], r[I + R]);
            Pairs<I + STEP, END, R, STEP, AW>::run(r);
        }
    }
};

template<int LO, int N, int R, int AW>
struct Merge {
    static __device__ __forceinline__ void run(float (&r)[AW]) {
        if constexpr (2 * R < N) {
            Merge<LO,     N, 2 * R, AW>::run(r);
            Merge<LO + R, N, 2 * R, AW>::run(r);
            Pairs<LO + R, LO + N, R, 2 * R, AW>::run(r);
        } else {
            cswap(r[LO], r[LO + R]);
        }
    }
};

template<int LO, int N, int AW>
struct Sorter {
    static __device__ __forceinline__ void run(float (&r)[AW]) {
        if constexpr (N > 1) {
            Sorter<LO,         N / 2, AW>::run(r);
            Sorter<LO + N / 2, N / 2, AW>::run(r);
            Merge<LO, N, 1, AW>::run(r);
        }
    }
};

// sort prefix r[0..PW-1] of the 32-buffer, select rank k=(dg-1)>>1.
// dg in (PW/2, PW] => k in [PW/4, PW/2-1]; DCE prunes comparators feeding
// other ranks.
template <int PW>
__device__ __forceinline__ float sortsel(float (&r)[32], int dg) {
    Sorter<0, PW, 32>::run(r);
    const int k = (dg - 1) >> 1;
    constexpr int KLO = PW / 4;
    constexpr int KHI = (PW / 2 > 0) ? PW / 2 - 1 : 0;
    float med = r[KLO];
    #pragma unroll
    for (int t = KLO + 1; t <= KHI; ++t)   // k wave-uniform -> s_cmp + cndmask
        if (t == k) med = r[t];
    return med;
}

// ---------------- kernel 3: pipelined per-node median (dg <= 32) ----------------
// Persistent waves, grid-stride over nodes, 2-stage software pipeline:
// stage A issues node n+1's s_loads + scattered x-gathers; stage B sorts node n.
// Breaks the per-node ~2400cy serial latency chain (s_load -> gather -> sort)
// that left VALUBusy at 36% with one node per wave.

// stage A: issue loads for node n into r[32]; returns dg (0 for big nodes).
__device__ __forceinline__ int stageA(const float* __restrict__ x,
                                      const int* __restrict__ deg,
                                      const uint64_t* __restrict__ slots,
                                      int lane, int n, float (&r)[32], int& dg_out) {
    int dg = __builtin_amdgcn_readfirstlane(deg[n]);     // s_load, clamped <= CAP
    dg_out = dg;
    int dgc = (dg > 32) ? 0 : dg;                        // big nodes: no gather here
    const uint64_t* row = slots + (size_t)n * CAP;       // wave-uniform -> s_load
    #pragma unroll
    for (int j = 0; j < 32; ++j) {
        float v = INFINITY;
        if (j < dgc) {                                   // wave-uniform scalar branch
            uint64_t s = row[j];
            uint32_t src = (uint32_t)(s & 0xffffffffu);
            float    w   = __uint_as_float((uint32_t)(s >> 32));
            v = x[(size_t)src * DD + lane] * w;          // SGPR base + lane offset
        }
        r[j] = v;
    }
    return dgc;
}

// stage B: sort + select + store node n (skips dg>32; median_big owns those).
__device__ __forceinline__ void stageB(int lane, int n, int dg, float (&r)[32],
                                       float* __restrict__ out) {
    if (dg > 32) return;
    float med = 0.f;
    if (dg > 0) {
        if      (dg <= 2)  med = sortsel<2>(r, dg);
        else if (dg <= 4)  med = sortsel<4>(r, dg);
        else if (dg <= 8)  med = sortsel<8>(r, dg);
        else if (dg <= 16) med = sortsel<16>(r, dg);
        else               med = sortsel<32>(r, dg);
    }
    out[(size_t)n * DD + lane] = med;
}

__global__ __launch_bounds__(256, 4) void median_main(
    const float* __restrict__ x, const int* __restrict__ deg,
    const uint64_t* __restrict__ slots, float* __restrict__ out) {
    const int lane = threadIdx.x & 63;
    const int wid  = (blockIdx.x * blockDim.x + threadIdx.x) >> 6;
    const int S    = (gridDim.x * blockDim.x) >> 6;      // total waves

    float rA[32], rB[32];
    int dgA, dgB;

    int n = wid;
    if (n >= NN) return;
    stageA(x, deg, slots, lane, n, rA, dgA);
    int nA = n; n += S;

    while (n < NN) {
        stageA(x, deg, slots, lane, n, rB, dgB);   // issue next gathers
        int nB = n; n += S;
        stageB(lane, nA, dgA, rA, out);            // sort current (loads in flight)
        if (n < NN) {
            stageA(x, deg, slots, lane, n, rA, dgA);
            nA = n; n += S;
            stageB(lane, nB, dgB, rB, out);
        } else {
            stageB(lane, nB, dgB, rB, out);
            return;
        }
    }
    stageB(lane, nA, dgA, rA, out);
}

// ---------------- kernel 4: rare dg>32 nodes (full Batcher-64) ----------------
__global__ __launch_bounds__(256) void median_big(
    const float* __restrict__ x, const int* __restrict__ deg,
    const uint64_t* __restrict__ slots, const int* __restrict__ big_cnt,
    const int* __restrict__ big_list, float* __restrict__ out) {
    const int lane = threadIdx.x & 63;
    const int wid  = (blockIdx.x * blockDim.x + threadIdx.x) >> 6;
    const int S    = (gridDim.x * blockDim.x) >> 6;

    int cnt = __builtin_amdgcn_readfirstlane(big_cnt[0]);
    if (cnt > BIGMAX) cnt = BIGMAX;

    for (int i = wid; i < cnt; i += S) {
        int n  = __builtin_amdgcn_readfirstlane(big_list[i]);
        int dg = __builtin_amdgcn_readfirstlane(deg[n]);   // 33..48
        const uint64_t* row = slots + (size_t)n * CAP;
        float r[64];
        #pragma unroll
        for (int j = 0; j < 64; ++j) {
            float v = INFINITY;
            if (j < dg) {
                uint64_t s = row[j];
                uint32_t src = (uint32_t)(s & 0xffffffffu);
                float    w   = __uint_as_float((uint32_t)(s >> 32));
                v = x[(size_t)src * DD + lane] * w;
            }
            r[j] = v;
        }
        Sorter<0, 64, 64>::run(r);
        const int k = (dg - 1) >> 1;                       // 16..23
        float med = r[16];
        #pragma unroll
        for (int t = 17; t <= 31; ++t)
            if (t == k) med = r[t];
        out[(size_t)n * DD + lane] = med;
    }
}

extern "C" void kernel_launch(void* const* d_in, const int* in_sizes, int n_in,
                              void* d_out, int out_size, void* d_ws, size_t ws_size,
                              hipStream_t stream) {
    const float*  x  = (const float*)d_in[0];
    const int*    ei = (const int*)d_in[1];
    const float*  ew = (const float*)d_in[2];
    float* out = (float*)d_out;

    int*      bucket_cnt = (int*)d_ws;                       // [NB] + big_cnt at [NB]
    int*      big_cnt    = bucket_cnt + NB;
    int*      big_list   = (int*)((char*)d_ws + (1 << 12));
    int*      deg        = (int*)((char*)d_ws + (1 << 14));
    uint64_t* recs       = (uint64_t*)((char*)d_ws + (1 << 18));
    uint64_t* slots      = (uint64_t*)((char*)d_ws + (1 << 23));

    zero_cnt<<<(NB + 1 + 255) / 256, 256, 0, stream>>>(bucket_cnt);
    bucketize<<<(EE + EPW - 1) / EPW, 512, 0, stream>>>(ei, ew, bucket_cnt, recs);
    bin_dense<<<NB, 256, 0, stream>>>(bucket_cnt, recs, slots, deg, big_cnt, big_list);
    median_main<<<2048, 256, 0, stream>>>(x, deg, slots, out);
    median_big<<<16, 256, 0, stream>>>(x, deg, slots, big_cnt, big_list, out);
}

// Round 7
// 142.374 us; speedup vs baseline: 1.7175x; 1.7175x over previous
//
#include <hip/hip_runtime.h>
#include <stdint.h>
#include <math.h>

#define NN 50000
#define DD 64
#define EE 800000
#define BSZ 64                      // nodes per bucket
#define NB 782                      // ceil(NN / BSZ)
#define BCAP 1280                   // records per bucket; mean 1023, sd ~32 -> +8 sigma
#define EPW 4096                    // edges per bucketize workgroup -> 196 WGs
#define CAP 48                      // dense slots per node; P(deg>48) ~ 1e-6 total
#define BIGMAX 1024                 // capacity of the dg>32 node list (expected ~2)

// workspace layout (unchanged footprint, ends at 26.31 MiB):
//   [0, 3132B)         bucket_cnt[NB] + big_cnt (at index NB)
//   [4KB, 8KB)         big_list[BIGMAX]
//   [16KB, 216KB)      deg[NN]          (clamped to CAP)
//   [256KB, 8.27MB)    recs[NB][BCAP]   packed (w_bits<<32 | src<<6 | dst_local)
//   [8MiB, 26.31MiB)   slots[NN][CAP]   dense (w_bits<<32 | src)

// ---------------- kernel 0: zero bucket counters (+big_cnt) ----------------
__global__ void zero_cnt(int* __restrict__ cnt) {
    int i = blockIdx.x * blockDim.x + threadIdx.x;
    if (i < NB + 1) cnt[i] = 0;
}

// ---------------- kernel 1: counting-sort edges into dst-buckets ----------------
// LDS-staged single global read of the edge slice; per-WG LDS histogram; ONE
// global atomic per (WG,bucket) chunk; records stored into contiguous chunks.
__global__ __launch_bounds__(512) void bucketize(
        const int* __restrict__ ei, const float* __restrict__ ew,
        int* __restrict__ bucket_cnt, uint64_t* __restrict__ recs) {
    __shared__ int   hist[NB];
    __shared__ int   base[NB];
    __shared__ int   eL[EPW];
    __shared__ int   dL[EPW];
    __shared__ float wL[EPW];   // 48KB staging + 6.3KB hist/base
    const int t = threadIdx.x;
    const int e0 = blockIdx.x * EPW;
    const int nE = (e0 + EPW < EE) ? EPW : (EE - e0);

    for (int i = t; i < NB; i += 512) hist[i] = 0;
    for (int i = t; i < nE; i += 512) {         // stage edges once (coalesced)
        eL[i] = ei[e0 + i];
        dL[i] = ei[EE + e0 + i];
        wL[i] = ew[e0 + i];
    }
    __syncthreads();

    for (int i = t; i < nE; i += 512)           // pass 1: histogram (LDS atomics)
        atomicAdd(&hist[dL[i] >> 6], 1);
    __syncthreads();

    for (int i = t; i < NB; i += 512) {         // one global atomic per chunk
        int c = hist[i];
        base[i] = (c > 0) ? atomicAdd(&bucket_cnt[i], c) : 0;
        hist[i] = 0;                            // reuse as running offset
    }
    __syncthreads();

    for (int i = t; i < nE; i += 512) {         // pass 2: place records (from LDS)
        int d = dL[i];
        int b = d >> 6;
        int p = base[b] + atomicAdd(&hist[b], 1);
        if (p < BCAP)
            recs[(size_t)b * BCAP + p] =
                ((uint64_t)__float_as_uint(wL[i]) << 32) |
                ((uint32_t)eL[i] << 6) | (uint32_t)(d & 63);
    }
}

// ---------------- kernel 2: bin records into dense per-node slot rows ----------
// One WG per bucket. LDS atomics give dense positions; slot matrix streams out
// coalesced. Also emits the (rare) dg>32 node list for the big-median kernel.
__global__ __launch_bounds__(256) void bin_dense(
        const int* __restrict__ bucket_cnt, const uint64_t* __restrict__ recs,
        uint64_t* __restrict__ slots, int* __restrict__ deg,
        int* __restrict__ big_cnt, int* __restrict__ big_list) {
    __shared__ uint64_t sl[BSZ * CAP];          // 24.5 KB
    __shared__ int degl[BSZ];
    const int t = threadIdx.x;
    const int b = blockIdx.x;

    int cnt = bucket_cnt[b];
    if (cnt > BCAP) cnt = BCAP;

    for (int i = t; i < BSZ; i += 256) degl[i] = 0;
    __syncthreads();

    const uint64_t* br = recs + (size_t)b * BCAP;
    for (int i = t; i < cnt; i += 256) {
        uint64_t r = br[i];                     // coalesced
        int loc = (int)(r & 63u);
        int p = atomicAdd(&degl[loc], 1);       // LDS atomic -> dense positions
        if (p < CAP)
            sl[loc * CAP + p] = (r & 0xFFFFFFFF00000000ull)    // w_bits
                              | (uint32_t)(((uint32_t)r) >> 6); // src
    }
    __syncthreads();

    uint64_t* outrow = slots + (size_t)b * BSZ * CAP;
    for (int i = t; i < BSZ * CAP; i += 256) outrow[i] = sl[i];   // stream out
    int n0 = b * BSZ;
    for (int i = t; i < BSZ; i += 256) {
        int n = n0 + i;
        if (n < NN) {
            int dgi = degl[i];
            if (dgi > CAP) dgi = CAP;
            deg[n] = dgi;
            if (dgi > 32) {                     // expected ~2 nodes total
                int q = atomicAdd(big_cnt, 1);
                if (q < BIGMAX) big_list[q] = n;
            }
        }
    }
}

// ---------------- Batcher odd-even mergesort, all-constexpr indices ----------
__device__ __forceinline__ void cswap(float& a, float& b) {
    float lo = fminf(a, b);
    float hi = fmaxf(a, b);
    a = lo; b = hi;
}

template<int I, int END, int R, int STEP, int AW>
struct Pairs {
    static __device__ __forceinline__ void run(float (&r)[AW]) {
        if constexpr (I + R < END) {
            cswap(r[I], r[I + R]);
            Pairs<I + STEP, END, R, STEP, AW>::run(r);
        }
    }
};

template<int LO, int N, int R, int AW>
struct Merge {
    static __device__ __forceinline__ void run(float (&r)[AW]) {
        if constexpr (2 * R < N) {
            Merge<LO,     N, 2 * R, AW>::run(r);
            Merge<LO + R, N, 2 * R, AW>::run(r);
            Pairs<LO + R, LO + N, R, 2 * R, AW>::run(r);
        } else {
            cswap(r[LO], r[LO + R]);
        }
    }
};

template<int LO, int N, int AW>
struct Sorter {
    static __device__ __forceinline__ void run(float (&r)[AW]) {
        if constexpr (N > 1) {
            Sorter<LO,         N / 2, AW>::run(r);
            Sorter<LO + N / 2, N / 2, AW>::run(r);
            Merge<LO, N, 1, AW>::run(r);
        }
    }
};

// gather dg weighted rows (pad +inf to PW), sort, pick rank k.
// `row` is wave-uniform -> slot reads compile to s_load (SGPR), gather
// addressing is all-SALU, no readlane broadcasts needed.
// dg in (PW/2, PW] => k in [PW/4, PW/2-1]; DCE prunes other-rank comparators.
template <int PW>
__device__ __forceinline__ float gather_sort_u(const float* __restrict__ x, int lane,
                                               int dg, int k,
                                               const uint64_t* __restrict__ row) {
    float r[PW];
    #pragma unroll
    for (int j = 0; j < PW; ++j) {
        float v = INFINITY;
        if (j < dg) {                      // wave-uniform -> scalar branch
            uint64_t s = row[j];           // uniform addr -> s_load
            uint32_t src = (uint32_t)(s & 0xffffffffu);
            float    w   = __uint_as_float((uint32_t)(s >> 32));
            v = x[(size_t)src * DD + lane] * w;   // SGPR base + lane offset
        }
        r[j] = v;
    }
    Sorter<0, PW, PW>::run(r);
    constexpr int KLO = PW / 4;
    constexpr int KHI = (PW / 2 > 0) ? PW / 2 - 1 : 0;
    float med = r[KLO];
    #pragma unroll
    for (int t = KLO + 1; t <= KHI; ++t)   // k wave-uniform -> s_cmp + cndmask
        if (t == k) med = r[t];
    return med;
}

// ---------------- kernel 3: persistent-wave per-node median (dg <= 32) --------
// Round-5 per-node code (44 VGPR, no spills) + grid-stride persistence:
// exactly 2048 blocks = 8192 waves = 32 waves/CU stay resident for the whole
// kernel, eliminating the ~250 block-dispatch/us churn that capped residency
// at ~38% when one 4-wave block retired every ~2us. Latency hiding is
// wave-level TLP (8 waves/SIMD), NOT intra-wave pipelining (round 6: the
// rA/rB double-buffer ate the whole VGPR budget -> scratch spills, 3x slower).
__global__ __launch_bounds__(256, 4) void median_main(
    const float* __restrict__ x, const int* __restrict__ deg,
    const uint64_t* __restrict__ slots, float* __restrict__ out) {
    const int lane = threadIdx.x & 63;
    const int wid  = (blockIdx.x * blockDim.x + threadIdx.x) >> 6;
    const int S    = (gridDim.x * blockDim.x) >> 6;      // total waves (8192)

    for (int n0 = wid; n0 < NN; n0 += S) {
        const int n = __builtin_amdgcn_readfirstlane(n0);          // force SGPR
        int dg = __builtin_amdgcn_readfirstlane(deg[n]);
        if (dg > 32) continue;                 // median_big owns 33..48

        float med = 0.f;
        if (dg > 0) {
            const uint64_t* row = slots + (size_t)n * CAP;   // wave-uniform ptr
            const int k = (dg - 1) >> 1;
            if      (dg <= 2)  med = gather_sort_u<2>(x, lane, dg, k, row);
            else if (dg <= 4)  med = gather_sort_u<4>(x, lane, dg, k, row);
            else if (dg <= 8)  med = gather_sort_u<8>(x, lane, dg, k, row);
            else if (dg <= 16) med = gather_sort_u<16>(x, lane, dg, k, row);
            else               med = gather_sort_u<32>(x, lane, dg, k, row);
        }
        out[(size_t)n * DD + lane] = med;
    }
}

// ---------------- kernel 4: rare dg>32 nodes (full Batcher-64) ----------------
__global__ __launch_bounds__(256) void median_big(
    const float* __restrict__ x, const int* __restrict__ deg,
    const uint64_t* __restrict__ slots, const int* __restrict__ big_cnt,
    const int* __restrict__ big_list, float* __restrict__ out) {
    const int lane = threadIdx.x & 63;
    const int wid  = (blockIdx.x * blockDim.x + threadIdx.x) >> 6;
    const int S    = (gridDim.x * blockDim.x) >> 6;

    int cnt = __builtin_amdgcn_readfirstlane(big_cnt[0]);
    if (cnt > BIGMAX) cnt = BIGMAX;

    for (int i = wid; i < cnt; i += S) {
        int n  = __builtin_amdgcn_readfirstlane(big_list[i]);
        int dg = __builtin_amdgcn_readfirstlane(deg[n]);   // 33..48
        const uint64_t* row = slots + (size_t)n * CAP;
        float r[64];
        #pragma unroll
        for (int j = 0; j < 64; ++j) {
            float v = INFINITY;
            if (j < dg) {
                uint64_t s = row[j];
                uint32_t src = (uint32_t)(s & 0xffffffffu);
                float    w   = __uint_as_float((uint32_t)(s >> 32));
                v = x[(size_t)src * DD + lane] * w;
            }
            r[j] = v;
        }
        Sorter<0, 64, 64>::run(r);
        const int k = (dg - 1) >> 1;                       // 16..23
        float med = r[16];
        #pragma unroll
        for (int t = 17; t <= 31; ++t)
            if (t == k) med = r[t];
        out[(size_t)n * DD + lane] = med;
    }
}

extern "C" void kernel_launch(void* const* d_in, const int* in_sizes, int n_in,
                              void* d_out, int out_size, void* d_ws, size_t ws_size,
                              hipStream_t stream) {
    const float*  x  = (const float*)d_in[0];
    const int*    ei = (const int*)d_in[1];
    const float*  ew = (const float*)d_in[2];
    float* out = (float*)d_out;

    int*      bucket_cnt = (int*)d_ws;                       // [NB] + big_cnt at [NB]
    int*      big_cnt    = bucket_cnt + NB;
    int*      big_list   = (int*)((char*)d_ws + (1 << 12));
    int*      deg        = (int*)((char*)d_ws + (1 << 14));
    uint64_t* recs       = (uint64_t*)((char*)d_ws + (1 << 18));
    uint64_t* slots      = (uint64_t*)((char*)d_ws + (1 << 23));

    zero_cnt<<<(NB + 1 + 255) / 256, 256, 0, stream>>>(bucket_cnt);
    bucketize<<<(EE + EPW - 1) / EPW, 512, 0, stream>>>(ei, ew, bucket_cnt, recs);
    bin_dense<<<NB, 256, 0, stream>>>(bucket_cnt, recs, slots, deg, big_cnt, big_list);
    median_main<<<2048, 256, 0, stream>>>(x, deg, slots, out);
    median_big<<<16, 256, 0, stream>>>(x, deg, slots, big_cnt, big_list, out);
}